// Round 6
// baseline (415.342 us; speedup 1.0000x reference)
//
#include <hip/hip_runtime.h>
#include <hip/hip_bf16.h>

// GraphSAGE 2-layer, wave-independent fusion:
//   each 64-lane wave owns one 16-row output tile end to end:
//   gathers A-fragments (self half + mean-of-10 half) straight from global
//   into registers in MFMA fragment layout, streams B from L2-resident W,
//   accumulates 16 n-frags, relu+store. No LDS, no barriers.
// N_RAW=200000, N1=100000 (6250 tiles of 16), N2=20000 (1250 tiles), D=256, OUT=256.

typedef __attribute__((ext_vector_type(8))) short bf16x8;
typedef __attribute__((ext_vector_type(4))) float f32x4;

static __device__ __forceinline__ short f2bf(float f) {
  __hip_bfloat16 h = __float2bfloat16(f);
  return *reinterpret_cast<short*>(&h);
}
static __device__ __forceinline__ float bf2f(short s) {
  union { unsigned u; float f; } x;
  x.u = ((unsigned)(unsigned short)s) << 16;
  return x.f;
}

// ---------------- one-shot f32 -> bf16: raw (25000 blocks) + W1 (64) + W2 (64) ----------------
// Non-temporal f32 reads: don't cache the 205 MB source stream, so the bf16
// destination (rawb, 102 MB) stays LLC-resident for the gather that follows.
__global__ __launch_bounds__(256) void convert_all(
    const float* __restrict__ raw, const float* __restrict__ W1,
    const float* __restrict__ W2, short* __restrict__ rawb,
    short* __restrict__ W1b, short* __restrict__ W2b) {
  const int b = blockIdx.x;
  const float* src;
  short* dst;
  size_t base;
  if (b < 25000) { src = raw; dst = rawb; base = (size_t)b * 2048; }
  else if (b < 25064) { src = W1; dst = W1b; base = (size_t)(b - 25000) * 2048; }
  else { src = W2; dst = W2b; base = (size_t)(b - 25064) * 2048; }
  const size_t i = base + (size_t)threadIdx.x * 8;
  const f32x4* s4 = reinterpret_cast<const f32x4*>(src + i);
  f32x4 u = __builtin_nontemporal_load(s4);
  f32x4 v = __builtin_nontemporal_load(s4 + 1);
  bf16x8 o;
  o[0] = f2bf(u.x); o[1] = f2bf(u.y); o[2] = f2bf(u.z); o[3] = f2bf(u.w);
  o[4] = f2bf(v.x); o[5] = f2bf(v.y); o[6] = f2bf(v.z); o[7] = f2bf(v.w);
  *reinterpret_cast<bf16x8*>(dst + i) = o;
}

// ---------------- wave-independent fused layer ----------------
// Wave w handles rows [tile*16, tile*16+16). Lane l: row = tile*16 + (l&15),
// chunk-group cg = l>>4 (8 bf16 = 16 B per chunk).
// A-frag for k-step ks: elements k = ks*32 + cg*8 .. +8 of the combined row
//   ks 0..7  -> self row E[self_idx[row]]
//   ks 8..15 -> mean over 10 neighbor rows (computed in-register)
// B-frag: W row (= output col) nf*16 + (l&15), same k window.
template <bool OUT_BF16>
__global__ __launch_bounds__(256) void sage_wave(
    const short* __restrict__ E,        // [Ne][256] bf16 embeddings
    const int* __restrict__ self_idx,   // [Nv]
    const int* __restrict__ neigh,      // [Nv][10]
    const short* __restrict__ Wb,       // [256][512] bf16 (W row-major)
    void* __restrict__ out,             // [Nv][256] (bf16 or f32)
    int ntiles) {
  const int lane = threadIdx.x & 63;
  const int wv = threadIdx.x >> 6;
  const int tile = blockIdx.x * 4 + wv;
  if (tile >= ntiles) return;

  const int row = tile * 16 + (lane & 15);
  const int cg = lane >> 4;

  const unsigned selfoff = (unsigned)self_idx[row] * 256u;
  unsigned nboff[10];
#pragma unroll
  for (int j = 0; j < 10; ++j) nboff[j] = (unsigned)neigh[row * 10 + j] * 256u;

  const short* Wl = Wb + (lane & 15) * 512 + cg * 8;  // + nf*8192 + ks*32

  f32x4 acc[16];
#pragma unroll
  for (int i = 0; i < 16; ++i) acc[i] = f32x4{0.f, 0.f, 0.f, 0.f};

  bf16x8 aCur = *reinterpret_cast<const bf16x8*>(E + selfoff + cg * 8);

  // ---- phase 1: self half (ks 0..7); prefetch next A one step ahead ----
#pragma unroll
  for (int ks = 0; ks < 8; ++ks) {
    bf16x8 aNxt;
    bf16x8 vst[10];
    if (ks < 7) {
      aNxt = *reinterpret_cast<const bf16x8*>(E + selfoff + (ks + 1) * 32 + cg * 8);
    } else {  // prefetch first mean chunk (ks=8): offset 0
#pragma unroll
      for (int j = 0; j < 10; ++j)
        vst[j] = *reinterpret_cast<const bf16x8*>(E + nboff[j] + cg * 8);
    }
#pragma unroll
    for (int nf = 0; nf < 16; ++nf) {
      bf16x8 b = *reinterpret_cast<const bf16x8*>(Wl + nf * 8192 + ks * 32);
      acc[nf] = __builtin_amdgcn_mfma_f32_16x16x32_bf16(aCur, b, acc[nf], 0, 0, 0);
    }
    if (ks < 7) {
      aCur = aNxt;
    } else {
#pragma unroll
      for (int j = 0; j < 8; ++j) {
        float sA = bf2f(vst[0][j]) + bf2f(vst[2][j]) + bf2f(vst[4][j]) + bf2f(vst[6][j]) + bf2f(vst[8][j]);
        float sB = bf2f(vst[1][j]) + bf2f(vst[3][j]) + bf2f(vst[5][j]) + bf2f(vst[7][j]) + bf2f(vst[9][j]);
        aCur[j] = f2bf((sA + sB) * 0.1f);
      }
    }
  }

  // ---- phase 2: mean half (ks 8..15); 10 loads for ks+1 fly under ks's MFMAs ----
#pragma unroll
  for (int ks = 8; ks < 16; ++ks) {
    bf16x8 vst[10];
    if (ks < 15) {
#pragma unroll
      for (int j = 0; j < 10; ++j)
        vst[j] = *reinterpret_cast<const bf16x8*>(E + nboff[j] + (ks - 7) * 32 + cg * 8);
    }
#pragma unroll
    for (int nf = 0; nf < 16; ++nf) {
      bf16x8 b = *reinterpret_cast<const bf16x8*>(Wl + nf * 8192 + ks * 32);
      acc[nf] = __builtin_amdgcn_mfma_f32_16x16x32_bf16(aCur, b, acc[nf], 0, 0, 0);
    }
    if (ks < 15) {
#pragma unroll
      for (int j = 0; j < 8; ++j) {
        float sA = bf2f(vst[0][j]) + bf2f(vst[2][j]) + bf2f(vst[4][j]) + bf2f(vst[6][j]) + bf2f(vst[8][j]);
        float sB = bf2f(vst[1][j]) + bf2f(vst[3][j]) + bf2f(vst[5][j]) + bf2f(vst[7][j]) + bf2f(vst[9][j]);
        aCur[j] = f2bf((sA + sB) * 0.1f);
      }
    }
  }

  // ---- epilogue: relu + store (C/D layout: col=lane&15, row=cg*4+r) ----
#pragma unroll
  for (int nf = 0; nf < 16; ++nf)
#pragma unroll
    for (int r = 0; r < 4; ++r) {
      const int gm = tile * 16 + cg * 4 + r;
      const int gn = nf * 16 + (lane & 15);
      float v = acc[nf][r];
      v = v > 0.f ? v : 0.f;
      if (OUT_BF16)
        reinterpret_cast<short*>(out)[(size_t)gm * 256 + gn] = f2bf(v);
      else
        reinterpret_cast<float*>(out)[(size_t)gm * 256 + gn] = v;
    }
}

extern "C" void kernel_launch(void* const* d_in, const int* in_sizes, int n_in,
                              void* d_out, int out_size, void* d_ws, size_t ws_size,
                              hipStream_t stream) {
  const float* raw = (const float*)d_in[0];
  const float* W1 = (const float*)d_in[1];
  const float* W2 = (const float*)d_in[2];
  const int* nodes1 = (const int*)d_in[3];
  const int* neigh1 = (const int*)d_in[4];
  const int* self2 = (const int*)d_in[5];
  const int* neigh2 = (const int*)d_in[6];
  float* out = (float*)d_out;

  const int N_RAW = 200000, N1 = 100000;

  short* rawb = (short*)d_ws;                         // 200000*256 bf16 = 102.4 MB
  short* h1 = rawb + (size_t)N_RAW * 256;             // 100000*256 bf16 = 51.2 MB
  short* W1b = h1 + (size_t)N1 * 256;                 // 131072 bf16
  short* W2b = W1b + 131072;                          // 131072 bf16

  convert_all<<<25128, 256, 0, stream>>>(raw, W1, W2, rawb, W1b, W2b);

  // L1: 6250 16-row tiles, 4 waves/block -> 1563 blocks (2 idle waves in last)
  sage_wave<true><<<1563, 256, 0, stream>>>(rawb, nodes1, neigh1, W1b, h1, 6250);
  // L2: 1250 tiles -> 313 blocks
  sage_wave<false><<<313, 256, 0, stream>>>(h1, self2, neigh2, W2b, out, 1250);
}

// Round 7
// 224.852 us; speedup vs baseline: 1.8472x; 1.8472x over previous
//
#include <hip/hip_runtime.h>
#include <hip/hip_bf16.h>

// GraphSAGE 2-layer, fused per-block {pipelined gather+mean -> LDS} then {MFMA GEMM}.
// N_RAW=200000, N1=100000 (3125 tiles of 32), N2=20000 (625 tiles), D=256, OUT=256.
// Round-3 structure + 2-deep row pipeline in the gather (T14: issue-early, reduce-late).

typedef __attribute__((ext_vector_type(8))) short bf16x8;
typedef __attribute__((ext_vector_type(4))) float f32x4;

static __device__ __forceinline__ short f2bf(float f) {
  __hip_bfloat16 h = __float2bfloat16(f);
  return *reinterpret_cast<short*>(&h);
}
static __device__ __forceinline__ float bf2f(short s) {
  union { unsigned u; float f; } x;
  x.u = ((unsigned)(unsigned short)s) << 16;
  return x.f;
}

// ---------------- one-shot f32 -> bf16: raw (25000 blocks) + W1 (64) + W2 (64) ----------------
// Non-temporal f32 reads: don't pollute L2/LLC with the 205 MB source stream,
// so rawb (102 MB) stays LLC-resident for the gather that follows.
__global__ __launch_bounds__(256) void convert_all(
    const float* __restrict__ raw, const float* __restrict__ W1,
    const float* __restrict__ W2, short* __restrict__ rawb,
    short* __restrict__ W1b, short* __restrict__ W2b) {
  const int b = blockIdx.x;
  const float* src;
  short* dst;
  size_t base;
  if (b < 25000) { src = raw; dst = rawb; base = (size_t)b * 2048; }
  else if (b < 25064) { src = W1; dst = W1b; base = (size_t)(b - 25000) * 2048; }
  else { src = W2; dst = W2b; base = (size_t)(b - 25064) * 2048; }
  const size_t i = base + (size_t)threadIdx.x * 8;
  const f32x4* s4 = reinterpret_cast<const f32x4*>(src + i);
  f32x4 u = __builtin_nontemporal_load(s4);
  f32x4 v = __builtin_nontemporal_load(s4 + 1);
  bf16x8 o;
  o[0] = f2bf(u.x); o[1] = f2bf(u.y); o[2] = f2bf(u.z); o[3] = f2bf(u.w);
  o[4] = f2bf(v.x); o[5] = f2bf(v.y); o[6] = f2bf(v.z); o[7] = f2bf(v.w);
  *reinterpret_cast<bf16x8*>(dst + i) = o;
}

// ---------------- fused layer: pipelined gather+mean -> LDS -> relu(comb @ W^T) ----------------
// Block: 32 rows x 256 cols, 256 threads (4 waves).
// Gather: thread (c=tid&31, rs=tid>>5) handles rows rs*4+rr, rr=0..3, chunk c (16 B).
//   2-deep pipeline: batch rr+1's 11 loads are in flight while batch rr reduces.
// GEMM: 4 waves x (32 rows x 64 cols), A from LDS, B streamed from L2-resident W,
//   1 k-step ahead register pipeline.
template <bool OUT_BF16>
__global__ __launch_bounds__(256, 4) void sage_fused(
    const short* __restrict__ E,        // [Ne][256] bf16 embeddings
    const int* __restrict__ self_idx,   // [Nv]
    const int* __restrict__ neigh,      // [Nv][10]
    const short* __restrict__ Wb,       // [256][512] bf16 (W row-major)
    void* __restrict__ out) {           // [Nv][256] (bf16 or f32)
  __shared__ short As[32][520];

  const int tid = threadIdx.x;
  const int m0 = blockIdx.x * 32;
  const int c = tid & 31;    // 16-B chunk (8 bf16) within 256-col row
  const int rs = tid >> 5;   // row slot 0..7 -> rows rs*4 .. rs*4+3

  // ---- gather + mean, 2-deep row pipeline ----
  {
    bf16x8 sv[2];
    bf16x8 v[2][10];

    // prologue: issue row rs*4+0's loads
    {
      const int gr = m0 + rs * 4;
      const int si = self_idx[gr];
      int nbx[10];
#pragma unroll
      for (int k = 0; k < 10; ++k) nbx[k] = neigh[gr * 10 + k];
      sv[0] = *reinterpret_cast<const bf16x8*>(E + (size_t)si * 256 + c * 8);
#pragma unroll
      for (int k = 0; k < 10; ++k)
        v[0][k] = *reinterpret_cast<const bf16x8*>(E + (size_t)nbx[k] * 256 + c * 8);
    }

#pragma unroll
    for (int rr = 0; rr < 4; ++rr) {
      const int cur = rr & 1, nxt = cur ^ 1;
      if (rr < 3) {  // issue next row's loads before consuming current
        const int gr = m0 + rs * 4 + rr + 1;
        const int si = self_idx[gr];
        int nbx[10];
#pragma unroll
        for (int k = 0; k < 10; ++k) nbx[k] = neigh[gr * 10 + k];
        sv[nxt] = *reinterpret_cast<const bf16x8*>(E + (size_t)si * 256 + c * 8);
#pragma unroll
        for (int k = 0; k < 10; ++k)
          v[nxt][k] = *reinterpret_cast<const bf16x8*>(E + (size_t)nbx[k] * 256 + c * 8);
      }
      // reduce current batch, write LDS
      const int r = rs * 4 + rr;
      bf16x8 mv;
#pragma unroll
      for (int j = 0; j < 8; ++j) {
        float sA = bf2f(v[cur][0][j]) + bf2f(v[cur][2][j]) + bf2f(v[cur][4][j]) +
                   bf2f(v[cur][6][j]) + bf2f(v[cur][8][j]);
        float sB = bf2f(v[cur][1][j]) + bf2f(v[cur][3][j]) + bf2f(v[cur][5][j]) +
                   bf2f(v[cur][7][j]) + bf2f(v[cur][9][j]);
        mv[j] = f2bf((sA + sB) * 0.1f);
      }
      *reinterpret_cast<bf16x8*>(&As[r][c * 8]) = sv[cur];
      *reinterpret_cast<bf16x8*>(&As[r][256 + c * 8]) = mv;
    }
  }
  __syncthreads();

  // ---- GEMM phase: 32x256 = 4 waves x (32x64), K=512, 1-step pipelined ----
  const int wave = tid >> 6, lane = tid & 63;
  const int wn = wave * 64;
  const int lr = lane & 15;           // m (A) / n (B) within 16x16 frag
  const int lkb = (lane >> 4) * 8;    // k base within 32
  const short* Bp = Wb + (size_t)(wn + lr) * 512 + lkb;  // + ni*8192 + k0

  f32x4 acc[2][4] = {};

  bf16x8 a0 = *reinterpret_cast<const bf16x8*>(&As[lr][lkb]);
  bf16x8 a1 = *reinterpret_cast<const bf16x8*>(&As[16 + lr][lkb]);
  bf16x8 b0 = *reinterpret_cast<const bf16x8*>(Bp + 0 * 8192);
  bf16x8 b1 = *reinterpret_cast<const bf16x8*>(Bp + 1 * 8192);
  bf16x8 b2 = *reinterpret_cast<const bf16x8*>(Bp + 2 * 8192);
  bf16x8 b3 = *reinterpret_cast<const bf16x8*>(Bp + 3 * 8192);

#pragma unroll
  for (int ks = 0; ks < 16; ++ks) {
    bf16x8 na0, na1, nb0, nb1, nb2, nb3;
    if (ks < 15) {
      const int k0 = (ks + 1) * 32;
      na0 = *reinterpret_cast<const bf16x8*>(&As[lr][k0 + lkb]);
      na1 = *reinterpret_cast<const bf16x8*>(&As[16 + lr][k0 + lkb]);
      nb0 = *reinterpret_cast<const bf16x8*>(Bp + k0 + 0 * 8192);
      nb1 = *reinterpret_cast<const bf16x8*>(Bp + k0 + 1 * 8192);
      nb2 = *reinterpret_cast<const bf16x8*>(Bp + k0 + 2 * 8192);
      nb3 = *reinterpret_cast<const bf16x8*>(Bp + k0 + 3 * 8192);
    }
    __builtin_amdgcn_s_setprio(1);
    acc[0][0] = __builtin_amdgcn_mfma_f32_16x16x32_bf16(a0, b0, acc[0][0], 0, 0, 0);
    acc[1][0] = __builtin_amdgcn_mfma_f32_16x16x32_bf16(a1, b0, acc[1][0], 0, 0, 0);
    acc[0][1] = __builtin_amdgcn_mfma_f32_16x16x32_bf16(a0, b1, acc[0][1], 0, 0, 0);
    acc[1][1] = __builtin_amdgcn_mfma_f32_16x16x32_bf16(a1, b1, acc[1][1], 0, 0, 0);
    acc[0][2] = __builtin_amdgcn_mfma_f32_16x16x32_bf16(a0, b2, acc[0][2], 0, 0, 0);
    acc[1][2] = __builtin_amdgcn_mfma_f32_16x16x32_bf16(a1, b2, acc[1][2], 0, 0, 0);
    acc[0][3] = __builtin_amdgcn_mfma_f32_16x16x32_bf16(a0, b3, acc[0][3], 0, 0, 0);
    acc[1][3] = __builtin_amdgcn_mfma_f32_16x16x32_bf16(a1, b3, acc[1][3], 0, 0, 0);
    __builtin_amdgcn_s_setprio(0);
    a0 = na0; a1 = na1; b0 = nb0; b1 = nb1; b2 = nb2; b3 = nb3;
  }

  // ---- epilogue: relu + store ----
#pragma unroll
  for (int mi = 0; mi < 2; ++mi)
#pragma unroll
    for (int ni = 0; ni < 4; ++ni)
#pragma unroll
      for (int r = 0; r < 4; ++r) {
        const int gm = m0 + mi * 16 + (lane >> 4) * 4 + r;
        const int gn = wn + ni * 16 + lr;
        float v = acc[mi][ni][r];
        v = v > 0.f ? v : 0.f;
        if (OUT_BF16)
          reinterpret_cast<short*>(out)[(size_t)gm * 256 + gn] = f2bf(v);
        else
          reinterpret_cast<float*>(out)[(size_t)gm * 256 + gn] = v;
      }
}

extern "C" void kernel_launch(void* const* d_in, const int* in_sizes, int n_in,
                              void* d_out, int out_size, void* d_ws, size_t ws_size,
                              hipStream_t stream) {
  const float* raw = (const float*)d_in[0];
  const float* W1 = (const float*)d_in[1];
  const float* W2 = (const float*)d_in[2];
  const int* nodes1 = (const int*)d_in[3];
  const int* neigh1 = (const int*)d_in[4];
  const int* self2 = (const int*)d_in[5];
  const int* neigh2 = (const int*)d_in[6];
  float* out = (float*)d_out;

  const int N_RAW = 200000, N1 = 100000;

  short* rawb = (short*)d_ws;                         // 200000*256 bf16 = 102.4 MB
  short* h1 = rawb + (size_t)N_RAW * 256;             // 100000*256 bf16 = 51.2 MB
  short* W1b = h1 + (size_t)N1 * 256;                 // 131072 bf16
  short* W2b = W1b + 131072;                          // 131072 bf16

  convert_all<<<25128, 256, 0, stream>>>(raw, W1, W2, rawb, W1b, W2b);
  sage_fused<true><<<3125, 256, 0, stream>>>(rawb, nodes1, neigh1, W1b, h1);
  sage_fused<false><<<625, 256, 0, stream>>>(h1, self2, neigh2, W2b, out);
}